// Round 4
// baseline (186.868 us; speedup 1.0000x reference)
//
#include <hip/hip_runtime.h>
#include <math.h>

// out = sum_j W[j] * (sum_n |yt[n,j]-yp[n,j]|) / (sum_n yt[n,j])
// (outer mean's 1/N cancels the 1/N inside col_mean)
//
// Memory-bound: 167.8 MB read. Floor ~27 us @ 6.3 TB/s.
//
// R4: the compiler sank every previous attempt at MLP back to a 2-3 load
// window (VGPR_Count 32/36 in R1-R3, time pinned ~63us). Here each batch is
//   [issue 10 global_load_dwordx4] -> sched_barrier(0) -> [consume]
// __builtin_amdgcn_sched_barrier(0) forbids ANY instruction from crossing,
// so all 10 results must stay live (40 VGPRs) -> >=10 loads in flight/wave.
// GRID*BLOCK = 524288 threads = 8192 waves = 32 waves/CU demand; keep
// VGPR <= 64 so full occupancy is legal.
//
// Column math (same as R2): float4 q=tid+k*TTH, component c -> column
// (4q+c)%5; 4*TTH mod 5 == 2 -> col = (c + 2k + 4*tid)%5. (c+2k)%5 is
// static after unroll; per-thread rotation un-done once at the end.

#define GRID 2048
#define BLOCK 256
#define TTH (GRID * BLOCK)  // 524288; 4*TTH mod 5 == 2
#define KLOADS 10           // 524288*10 = 5242880 float4s per array, exact
#define BAT 5               // float4-pairs per batch (10 loads in flight)

__global__ __launch_bounds__(BLOCK) void regress_reduce_fast(
    const float4* __restrict__ yt4, const float4* __restrict__ yp4,
    float* __restrict__ partials) {
  const int tid = blockIdx.x * BLOCK + threadIdx.x;

  // rotated-space accumulators: local m corresponds to column (m + 4*tid)%5
  float s[5] = {0.f, 0.f, 0.f, 0.f, 0.f};
  float a[5] = {0.f, 0.f, 0.f, 0.f, 0.f};

  float4 tv[BAT], pv[BAT];

#pragma unroll
  for (int b = 0; b < KLOADS / BAT; ++b) {
    // ---- issue phase: 10 independent dwordx4 loads ----
#pragma unroll
    for (int j = 0; j < BAT; ++j) {
      const int k = b * BAT + j;
      tv[j] = yt4[tid + (long long)k * TTH];
      pv[j] = yp4[tid + (long long)k * TTH];
    }
    __builtin_amdgcn_sched_barrier(0);  // nothing crosses: loads stay clustered
    // ---- consume phase ----
#pragma unroll
    for (int j = 0; j < BAT; ++j) {
      const int k = b * BAT + j;
      const int m0 = (2 * k + 0) % 5;  // static after unroll
      const int m1 = (2 * k + 1) % 5;
      const int m2 = (2 * k + 2) % 5;
      const int m3 = (2 * k + 3) % 5;
      const float4 t = tv[j], p = pv[j];
      s[m0] += t.x; a[m0] += fabsf(t.x - p.x);
      s[m1] += t.y; a[m1] += fabsf(t.y - p.y);
      s[m2] += t.z; a[m2] += fabsf(t.z - p.z);
      s[m3] += t.w; a[m3] += fabsf(t.w - p.w);
    }
    __builtin_amdgcn_sched_barrier(0);  // keep batches from merging/sinking
  }

  // un-rotate into global column space + block reduction via LDS
  __shared__ float red[BLOCK][11];  // +1 pad
  const int tix = threadIdx.x;
  const int rr = tid % 5;
#pragma unroll
  for (int m = 0; m < 5; ++m) {
    int g = m - rr; if (g < 0) g += 5;
    red[tix][g] = s[m];
    red[tix][5 + g] = a[m];
  }
  __syncthreads();
#pragma unroll
  for (int off = BLOCK / 2; off > 0; off >>= 1) {
    if (tix < off) {
#pragma unroll
      for (int v = 0; v < 10; ++v) red[tix][v] += red[tix + off][v];
    }
    __syncthreads();
  }
  if (tix < 10) partials[blockIdx.x * 10 + tix] = red[0][tix];  // deterministic
}

// generic fallback (any nrows), correctness-first
__global__ __launch_bounds__(BLOCK) void regress_reduce_generic(
    const float* __restrict__ yt, const float* __restrict__ yp,
    float* __restrict__ partials, long long nrows) {
  float s[5] = {0.f, 0.f, 0.f, 0.f, 0.f};
  float a[5] = {0.f, 0.f, 0.f, 0.f, 0.f};
  const long long tid = (long long)blockIdx.x * blockDim.x + threadIdx.x;
  const long long stride = (long long)gridDim.x * blockDim.x;
  for (long long r = tid; r < nrows; r += stride) {
#pragma unroll
    for (int c = 0; c < 5; ++c) {
      float tv = yt[r * 5 + c];
      s[c] += tv;
      a[c] += fabsf(tv - yp[r * 5 + c]);
    }
  }
  __shared__ float red[BLOCK][11];
  const int t = threadIdx.x;
#pragma unroll
  for (int c = 0; c < 5; ++c) { red[t][c] = s[c]; red[t][5 + c] = a[c]; }
  __syncthreads();
#pragma unroll
  for (int off = BLOCK / 2; off > 0; off >>= 1) {
    if (t < off) {
#pragma unroll
      for (int v = 0; v < 10; ++v) red[t][v] += red[t + off][v];
    }
    __syncthreads();
  }
  if (t < 10) partials[blockIdx.x * 10 + t] = red[0][t];
}

__global__ __launch_bounds__(256) void regress_finalize(
    const float* __restrict__ partials, int nblocks, float* __restrict__ out) {
  float acc[10] = {0.f, 0.f, 0.f, 0.f, 0.f, 0.f, 0.f, 0.f, 0.f, 0.f};
  for (int b = threadIdx.x; b < nblocks; b += 256) {
#pragma unroll
    for (int v = 0; v < 10; ++v) acc[v] += partials[b * 10 + v];
  }
#pragma unroll
  for (int off = 32; off > 0; off >>= 1) {
#pragma unroll
    for (int v = 0; v < 10; ++v) acc[v] += __shfl_down(acc[v], off, 64);
  }
  __shared__ float lds[4][10];
  const int lane = threadIdx.x & 63;
  const int wave = threadIdx.x >> 6;
  if (lane == 0) {
#pragma unroll
    for (int v = 0; v < 10; ++v) lds[wave][v] = acc[v];
  }
  __syncthreads();
  if (threadIdx.x == 0) {
    const float W[5] = {0.3f, 0.175f, 0.175f, 0.175f, 0.175f};
    float r = 0.f;
#pragma unroll
    for (int c = 0; c < 5; ++c) {
      float sc = lds[0][c] + lds[1][c] + lds[2][c] + lds[3][c];
      float ac = lds[0][5 + c] + lds[1][5 + c] + lds[2][5 + c] + lds[3][5 + c];
      r += W[c] * ac / sc;
    }
    *out = r;
  }
}

extern "C" void kernel_launch(void* const* d_in, const int* in_sizes, int n_in,
                              void* d_out, int out_size, void* d_ws, size_t ws_size,
                              hipStream_t stream) {
  const float* yt = (const float*)d_in[0];
  const float* yp = (const float*)d_in[1];
  const long long nelem = (long long)in_sizes[0];
  const long long nrows = nelem / 5;
  float* partials = (float*)d_ws;  // GRID * 10 floats = 80 KB

  if (nelem == (long long)TTH * KLOADS * 4) {
    regress_reduce_fast<<<GRID, BLOCK, 0, stream>>>(
        (const float4*)yt, (const float4*)yp, partials);
  } else {
    regress_reduce_generic<<<GRID, BLOCK, 0, stream>>>(yt, yp, partials, nrows);
  }
  regress_finalize<<<1, 256, 0, stream>>>(partials, GRID, (float*)d_out);
}

// Round 5
// 186.028 us; speedup vs baseline: 1.0045x; 1.0045x over previous
//
#include <hip/hip_runtime.h>
#include <math.h>
#include <stdint.h>

// out = sum_j W[j] * (sum_n |yt[n,j]-yp[n,j]|) / (sum_n yt[n,j])
// (outer mean's 1/N cancels the 1/N inside col_mean)
//
// R5: VGPR-result loads are queue-starved (~3.6 outstanding 1KB req/CU across
// R1-R4 regardless of pattern; compiler pins the load window at 2-3). Switch
// to the async DMA path: global_load_lds (16B/lane), whose MLP is bounded by
// vmcnt (<=63) + LDS space, not result VGPRs. m97 GEMM sustained >=52 GB/s/CU
// through this path (5x our R4 rate).
//
// Structure: 1280 blocks x 256 = 5120 waves; each wave owns a 4-slot ring
// (slot = 1KB yt chunk + 1KB yp chunk) in LDS. Pipeline: wait vmcnt(6) ->
// ds_read_b128 oldest slot -> accumulate -> DMA-issue next chunk-pair.
// Per-wave rings => NO barriers in the hot loop.
//
// Column math: float4 q, component c -> col (4q+c)%5. Wave W, chunk i=W+i*5120,
// lane L: q = (W+i*5120)*64 + L => 4q = W + 4L (mod 5) (5120=0, 256=1 mod 5).
// So col = (W + 4L + c)%5 is i-independent: 8 statically-indexed accumulators
// (c=0..3), un-rotated once at the end.

#define GRID 1280
#define BLOCK 256
#define NWAVES (GRID * 4)   // 5120, divisible by 5
#define CHUNKS 16           // per wave per array; 5120*16*64 = 5242880 float4s
#define RING 4              // slots in flight per wave
#define SLOT_BYTES 2048     // 1KB yt + 1KB yp

// wait until at most `n` vector-memory ops outstanding (gfx9 encoding;
// lgkmcnt=15, expcnt=7 i.e. don't-care)
#define WAITVM(n) __builtin_amdgcn_s_waitcnt(0x0F70 | ((n) & 15))

__device__ static inline void dma16(const void* g, void* l) {
  __builtin_amdgcn_global_load_lds(
      (const __attribute__((address_space(1))) void*)g,
      (__attribute__((address_space(3))) void*)l, 16, 0, 0);
}

__global__ __launch_bounds__(BLOCK) void regress_reduce_fast(
    const float4* __restrict__ yt4, const float4* __restrict__ yp4,
    float* __restrict__ partials) {
  __shared__ __align__(16) char ring[BLOCK / 64 * RING * SLOT_BYTES];  // 32 KB

  const int tix = threadIdx.x;
  const int lane = tix & 63;
  const int wv = tix >> 6;               // wave in block (0..3)
  const int W = blockIdx.x * 4 + wv;     // global wave id (0..5119)

  char* wring = ring + wv * (RING * SLOT_BYTES);  // this wave's 8 KB ring

  // per-lane global base: lane L of wave W reads float4 index (W + i*5120)*64 + L
  const float4* gt = yt4 + (long long)W * 64 + lane;
  const float4* gp = yp4 + (long long)W * 64 + lane;

  // prologue: fill the ring (4 chunk-pairs = 8 DMA loads in flight)
#pragma unroll
  for (int i = 0; i < RING; ++i) {
    char* slot = wring + i * SLOT_BYTES;
    dma16(gt + (long long)i * (NWAVES * 64), slot);
    dma16(gp + (long long)i * (NWAVES * 64), slot + 1024);
  }

  float s0 = 0.f, s1 = 0.f, s2 = 0.f, s3 = 0.f;
  float a0 = 0.f, a1 = 0.f, a2 = 0.f, a3 = 0.f;

#pragma unroll
  for (int i = 0; i < CHUNKS; ++i) {
    const int sl = i & (RING - 1);
    char* slot = wring + sl * SLOT_BYTES;
    WAITVM(2 * (RING - 1));  // oldest chunk-pair has landed in LDS
    const float4 tv = *(const float4*)(slot + lane * 16);
    const float4 pv = *(const float4*)(slot + 1024 + lane * 16);
    s0 += tv.x; a0 += fabsf(tv.x - pv.x);
    s1 += tv.y; a1 += fabsf(tv.y - pv.y);
    s2 += tv.z; a2 += fabsf(tv.z - pv.z);
    s3 += tv.w; a3 += fabsf(tv.w - pv.w);
    if (i + RING < CHUNKS) {  // refill the slot we just drained
      dma16(gt + (long long)(i + RING) * (NWAVES * 64), slot);
      dma16(gp + (long long)(i + RING) * (NWAVES * 64), slot + 1024);
    }
  }
  WAITVM(0);
  __syncthreads();  // all waves done with rings; reuse LDS for reduction

  // un-rotate: component c of this thread belongs to column (W + 4*lane + c)%5
  float(*red)[11] = (float(*)[11])ring;  // 256*11*4 = 11264 B <= 32 KB
  int r0 = (W + 4 * lane) % 5;
#pragma unroll
  for (int v = 0; v < 10; ++v) red[tix][v] = 0.f;
  {
    int g0 = r0;
    int g1 = r0 + 1; if (g1 >= 5) g1 -= 5;
    int g2 = r0 + 2; if (g2 >= 5) g2 -= 5;
    int g3 = r0 + 3; if (g3 >= 5) g3 -= 5;
    red[tix][g0] = s0; red[tix][5 + g0] = a0;
    red[tix][g1] = s1; red[tix][5 + g1] = a1;
    red[tix][g2] = s2; red[tix][5 + g2] = a2;
    red[tix][g3] = s3; red[tix][5 + g3] = a3;
  }
  __syncthreads();
#pragma unroll
  for (int off = BLOCK / 2; off > 0; off >>= 1) {
    if (tix < off) {
#pragma unroll
      for (int v = 0; v < 10; ++v) red[tix][v] += red[tix + off][v];
    }
    __syncthreads();
  }
  if (tix < 10) partials[blockIdx.x * 10 + tix] = red[0][tix];  // deterministic
}

// generic fallback (any nrows), correctness-first
__global__ __launch_bounds__(BLOCK) void regress_reduce_generic(
    const float* __restrict__ yt, const float* __restrict__ yp,
    float* __restrict__ partials, long long nrows) {
  float s[5] = {0.f, 0.f, 0.f, 0.f, 0.f};
  float a[5] = {0.f, 0.f, 0.f, 0.f, 0.f};
  const long long tid = (long long)blockIdx.x * blockDim.x + threadIdx.x;
  const long long stride = (long long)gridDim.x * blockDim.x;
  for (long long r = tid; r < nrows; r += stride) {
#pragma unroll
    for (int c = 0; c < 5; ++c) {
      float tv = yt[r * 5 + c];
      s[c] += tv;
      a[c] += fabsf(tv - yp[r * 5 + c]);
    }
  }
  __shared__ float red[BLOCK][11];
  const int t = threadIdx.x;
#pragma unroll
  for (int c = 0; c < 5; ++c) { red[t][c] = s[c]; red[t][5 + c] = a[c]; }
  __syncthreads();
#pragma unroll
  for (int off = BLOCK / 2; off > 0; off >>= 1) {
    if (t < off) {
#pragma unroll
      for (int v = 0; v < 10; ++v) red[t][v] += red[t + off][v];
    }
    __syncthreads();
  }
  if (t < 10) partials[blockIdx.x * 10 + t] = red[0][t];
}

__global__ __launch_bounds__(256) void regress_finalize(
    const float* __restrict__ partials, int nblocks, float* __restrict__ out) {
  float acc[10] = {0.f, 0.f, 0.f, 0.f, 0.f, 0.f, 0.f, 0.f, 0.f, 0.f};
  for (int b = threadIdx.x; b < nblocks; b += 256) {
#pragma unroll
    for (int v = 0; v < 10; ++v) acc[v] += partials[b * 10 + v];
  }
#pragma unroll
  for (int off = 32; off > 0; off >>= 1) {
#pragma unroll
    for (int v = 0; v < 10; ++v) acc[v] += __shfl_down(acc[v], off, 64);
  }
  __shared__ float lds[4][10];
  const int lane = threadIdx.x & 63;
  const int wave = threadIdx.x >> 6;
  if (lane == 0) {
#pragma unroll
    for (int v = 0; v < 10; ++v) lds[wave][v] = acc[v];
  }
  __syncthreads();
  if (threadIdx.x == 0) {
    const float W[5] = {0.3f, 0.175f, 0.175f, 0.175f, 0.175f};
    float r = 0.f;
#pragma unroll
    for (int c = 0; c < 5; ++c) {
      float sc = lds[0][c] + lds[1][c] + lds[2][c] + lds[3][c];
      float ac = lds[0][5 + c] + lds[1][5 + c] + lds[2][5 + c] + lds[3][5 + c];
      r += W[c] * ac / sc;
    }
    *out = r;
  }
}

extern "C" void kernel_launch(void* const* d_in, const int* in_sizes, int n_in,
                              void* d_out, int out_size, void* d_ws, size_t ws_size,
                              hipStream_t stream) {
  const float* yt = (const float*)d_in[0];
  const float* yp = (const float*)d_in[1];
  const long long nelem = (long long)in_sizes[0];
  const long long nrows = nelem / 5;
  float* partials = (float*)d_ws;  // GRID * 10 floats = 51.2 KB

  if (nelem == (long long)NWAVES * CHUNKS * 64 * 4) {
    regress_reduce_fast<<<GRID, BLOCK, 0, stream>>>(
        (const float4*)yt, (const float4*)yp, partials);
    regress_finalize<<<1, 256, 0, stream>>>(partials, GRID, (float*)d_out);
  } else {
    regress_reduce_generic<<<GRID, BLOCK, 0, stream>>>(yt, yp, partials, nrows);
    regress_finalize<<<1, 256, 0, stream>>>(partials, GRID, (float*)d_out);
  }
}

// Round 7
// 172.010 us; speedup vs baseline: 1.0864x; 1.0815x over previous
//
#include <hip/hip_runtime.h>
#include <math.h>

// out = sum_j W[j] * (sum_n |yt[n,j]-yp[n,j]|) / (sum_n yt[n,j])
// (outer mean's 1/N cancels the 1/N inside col_mean)
//
// R7 = R6 probe with compile fix: __builtin_nontemporal_load requires a
// native vector type, not HIP_vector_type. Use ext_vector_type(4).
//
// R1-R5 established: five different access mechanisms (uncoalesced VGPR,
// coalesced VGPR, batched, sched_barrier, global_load_lds DMA with 8 KB/wave
// in flight) ALL pin at 63-67 us = 2.58 TB/s read, FETCH 82 MB + ~84 MB LLC
// = exactly the input, VALU ~3%. Theory: per-CU outstanding-miss-line cap
// (TCP/MSHR) x LLC/HBM latency caps CU-issued read-only streaming at
// ~2.6 TB/s. nt (no-allocate) is the last cache-path knob: streaming data,
// zero reuse, L2 allocation is pure overhead. If neutral -> roofline.
//
// Column math (R2): float4 q = tid + k*TTH, component c -> col (4q+c)%5;
// 4*TTH mod 5 == 2 -> col = (c + 2k + 4*tid)%5. (c+2k)%5 static after
// unroll; per-thread rotation un-done once at the end.

#define GRID 2048
#define BLOCK 256
#define TTH (GRID * BLOCK)  // 524288; 4*TTH mod 5 == 2
#define KLOADS 10           // 524288*10 = 5242880 float4s per array, exact

typedef float vf4 __attribute__((ext_vector_type(4)));

__global__ __launch_bounds__(BLOCK) void regress_reduce_fast(
    const vf4* __restrict__ yt4, const vf4* __restrict__ yp4,
    float* __restrict__ partials) {
  const int tid = blockIdx.x * BLOCK + threadIdx.x;

  // rotated-space accumulators: local m corresponds to column (m + 4*tid)%5
  float s[5] = {0.f, 0.f, 0.f, 0.f, 0.f};
  float a[5] = {0.f, 0.f, 0.f, 0.f, 0.f};

#pragma unroll
  for (int k = 0; k < KLOADS; ++k) {
    const vf4 tv = __builtin_nontemporal_load(yt4 + tid + (long long)k * TTH);
    const vf4 pv = __builtin_nontemporal_load(yp4 + tid + (long long)k * TTH);
    const int m0 = (2 * k + 0) % 5;  // static after unroll
    const int m1 = (2 * k + 1) % 5;
    const int m2 = (2 * k + 2) % 5;
    const int m3 = (2 * k + 3) % 5;
    s[m0] += tv.x; a[m0] += fabsf(tv.x - pv.x);
    s[m1] += tv.y; a[m1] += fabsf(tv.y - pv.y);
    s[m2] += tv.z; a[m2] += fabsf(tv.z - pv.z);
    s[m3] += tv.w; a[m3] += fabsf(tv.w - pv.w);
  }

  // un-rotate into global column space + block reduction via LDS
  __shared__ float red[BLOCK][11];  // +1 pad
  const int tix = threadIdx.x;
  const int rr = tid % 5;
#pragma unroll
  for (int m = 0; m < 5; ++m) {
    int g = m - rr; if (g < 0) g += 5;
    red[tix][g] = s[m];
    red[tix][5 + g] = a[m];
  }
  __syncthreads();
#pragma unroll
  for (int off = BLOCK / 2; off > 0; off >>= 1) {
    if (tix < off) {
#pragma unroll
      for (int v = 0; v < 10; ++v) red[tix][v] += red[tix + off][v];
    }
    __syncthreads();
  }
  if (tix < 10) partials[blockIdx.x * 10 + tix] = red[0][tix];  // deterministic
}

// generic fallback (any nrows), correctness-first
__global__ __launch_bounds__(BLOCK) void regress_reduce_generic(
    const float* __restrict__ yt, const float* __restrict__ yp,
    float* __restrict__ partials, long long nrows) {
  float s[5] = {0.f, 0.f, 0.f, 0.f, 0.f};
  float a[5] = {0.f, 0.f, 0.f, 0.f, 0.f};
  const long long tid = (long long)blockIdx.x * blockDim.x + threadIdx.x;
  const long long stride = (long long)gridDim.x * blockDim.x;
  for (long long r = tid; r < nrows; r += stride) {
#pragma unroll
    for (int c = 0; c < 5; ++c) {
      float tv = yt[r * 5 + c];
      s[c] += tv;
      a[c] += fabsf(tv - yp[r * 5 + c]);
    }
  }
  __shared__ float red[BLOCK][11];
  const int t = threadIdx.x;
#pragma unroll
  for (int c = 0; c < 5; ++c) { red[t][c] = s[c]; red[t][5 + c] = a[c]; }
  __syncthreads();
#pragma unroll
  for (int off = BLOCK / 2; off > 0; off >>= 1) {
    if (t < off) {
#pragma unroll
      for (int v = 0; v < 10; ++v) red[t][v] += red[t + off][v];
    }
    __syncthreads();
  }
  if (t < 10) partials[blockIdx.x * 10 + t] = red[0][t];
}

__global__ __launch_bounds__(256) void regress_finalize(
    const float* __restrict__ partials, int nblocks, float* __restrict__ out) {
  float acc[10] = {0.f, 0.f, 0.f, 0.f, 0.f, 0.f, 0.f, 0.f, 0.f, 0.f};
  for (int b = threadIdx.x; b < nblocks; b += 256) {
#pragma unroll
    for (int v = 0; v < 10; ++v) acc[v] += partials[b * 10 + v];
  }
#pragma unroll
  for (int off = 32; off > 0; off >>= 1) {
#pragma unroll
    for (int v = 0; v < 10; ++v) acc[v] += __shfl_down(acc[v], off, 64);
  }
  __shared__ float lds[4][10];
  const int lane = threadIdx.x & 63;
  const int wave = threadIdx.x >> 6;
  if (lane == 0) {
#pragma unroll
    for (int v = 0; v < 10; ++v) lds[wave][v] = acc[v];
  }
  __syncthreads();
  if (threadIdx.x == 0) {
    const float W[5] = {0.3f, 0.175f, 0.175f, 0.175f, 0.175f};
    float r = 0.f;
#pragma unroll
    for (int c = 0; c < 5; ++c) {
      float sc = lds[0][c] + lds[1][c] + lds[2][c] + lds[3][c];
      float ac = lds[0][5 + c] + lds[1][5 + c] + lds[2][5 + c] + lds[3][5 + c];
      r += W[c] * ac / sc;
    }
    *out = r;
  }
}

extern "C" void kernel_launch(void* const* d_in, const int* in_sizes, int n_in,
                              void* d_out, int out_size, void* d_ws, size_t ws_size,
                              hipStream_t stream) {
  const float* yt = (const float*)d_in[0];
  const float* yp = (const float*)d_in[1];
  const long long nelem = (long long)in_sizes[0];
  const long long nrows = nelem / 5;
  float* partials = (float*)d_ws;  // GRID * 10 floats = 80 KB

  if (nelem == (long long)TTH * KLOADS * 4) {
    regress_reduce_fast<<<GRID, BLOCK, 0, stream>>>(
        (const vf4*)yt, (const vf4*)yp, partials);
  } else {
    regress_reduce_generic<<<GRID, BLOCK, 0, stream>>>(yt, yp, partials, nrows);
  }
  regress_finalize<<<1, 256, 0, stream>>>(partials, GRID, (float*)d_out);
}